// Round 12
// baseline (16.095 us; speedup 1.0000x reference)
//
#include <hip/hip_runtime.h>
#include <math.h>

#define LBL 16
#define B_TOTAL 32768
#define WAVES 16
#define BLOCK_THREADS 1024
#define COLS_PER_BLOCK 128
#define GRID_BLOCKS (B_TOTAL / COLS_PER_BLOCK)  // 256 = 1 block/CU

// LDS byte offsets (static 96 KB -> 1 block/CU, 16 waves = 4 waves/SIMD).
// [0, 32768)      U:  A1 table [qt][t][xrow 0..31][k=label 0..15] bf16(bit),
//                     state o=tile-offset placed at row x = swap-bits2<->3(o)
// [32768, 98304)  A2: [qt][t][sh][row 0..31][k=state 0..15] bf16;
//                     rows 0..15 = labels, row 16 = ones (z-row), 17..31 = 0
#define U_BOFF     0
#define A2_BOFF    32768
#define LDS_BYTES  98304

typedef __attribute__((ext_vector_type(8)))  short bf16x8;
typedef __attribute__((ext_vector_type(4)))  float f32x4;
typedef __attribute__((ext_vector_type(16))) float f32x16;

#define LOG2E 1.4426950408889634f

static __device__ __forceinline__ unsigned short bf16_rne(float x) {
    union { float f; unsigned u; } v; v.f = x;
    unsigned r = v.u + 0x7FFFu + ((v.u >> 16) & 1u);
    return (unsigned short)(r >> 16);
}
static __device__ __forceinline__ float bf16_to_f(unsigned short h) {
    union { unsigned u; float f; } v; v.u = ((unsigned)h) << 16;
    return v.f;
}
static __device__ __forceinline__ unsigned cvt_pk_bf16(float lo, float hi) {
    unsigned r;
    asm("v_cvt_pk_bf16_f32 %0, %1, %2" : "=v"(r) : "v"(lo), "v"(hi));
    return r;
}
// guaranteed single-instruction exp2 (no libcall risk); in-place friendly
static __device__ __forceinline__ float exp2_hw(float x) {
    float r;
    asm("v_exp_f32 %0, %1" : "=v"(r) : "v"(x));
    return r;
}

// pack bits l, l+1 of mask m as two bf16 (1.0/0.0) in one u32
#define PKB2(m, l) (((((m) >> (l)) & 1u) ? 0x3F80u : 0u) | ((((m) >> ((l) + 1)) & 1u) ? 0x3F800000u : 0u))
// pack bit r of masks a, b as two bf16 in one u32
#define PKR(a, b, r) (((((a) >> (r)) & 1u) ? 0x3F80u : 0u) | ((((b) >> (r)) & 1u) ? 0x3F800000u : 0u))

__global__ __launch_bounds__(BLOCK_THREADS, 4) void plm_mfma11(
    const float* __restrict__ f, const float* __restrict__ y,
    const int* __restrict__ S, float* __restrict__ out,
    float* __restrict__ block_loss)
{
    __shared__ __align__(16) unsigned char SHB[LDS_BYTES];
    __shared__ float wls[WAVES];
    unsigned* SH = (unsigned*)SHB;

    const int tid = threadIdx.x;
    const int w = tid >> 6, lane = tid & 63;
    const int qt = w >> 2;            // state quarter (256 states)
    const int cg = w & 3;             // column group (32 cols)
    const int col = lane & 31;        // batch col within group == MFMA row index
    const int kh = lane >> 5;         // k-chunk half (0: k 0..7, 1: k 8..15)
    const int b = blockIdx.x * COLS_PER_BLOCK + cg * 32 + col;

    // Epilogue mapping is tid-pure: prefetch y now (latency hides under kernel)
    const int lp = tid & 7;            // label pair
    const int col128 = tid >> 3;       // 0..127
    const int bg = blockIdx.x * COLS_PER_BLOCK + col128;
    const float2 yv = *(const float2*)(y + (size_t)bg * LBL + 2 * lp);

    // f prefetch (consumed after prologue)
    const float4* fr = (const float4*)(f + (size_t)b * LBL + kh * 8);
    float4 fx0 = fr[0], fx1 = fr[1];

    // ---------------- Merged prologue (single barrier) ----------------
    {
        // phase A: thread = state s; build U row, keep mask in register
        const int s = tid;
        const int4* sp = (const int4*)(S + (size_t)s * LBL);
        int4 ra = sp[0], rb = sp[1], rc = sp[2], rd = sp[3];
        unsigned m = (ra.x>0?1u:0u)       | ((ra.y>0?1u:0u)<<1)  | ((ra.z>0?1u:0u)<<2)  | ((ra.w>0?1u:0u)<<3)
                   | ((rb.x>0?1u:0u)<<4)  | ((rb.y>0?1u:0u)<<5)  | ((rb.z>0?1u:0u)<<6)  | ((rb.w>0?1u:0u)<<7)
                   | ((rc.x>0?1u:0u)<<8)  | ((rc.y>0?1u:0u)<<9)  | ((rc.z>0?1u:0u)<<10) | ((rc.w>0?1u:0u)<<11)
                   | ((rd.x>0?1u:0u)<<12) | ((rd.y>0?1u:0u)<<13) | ((rd.z>0?1u:0u)<<14) | ((rd.w>0?1u:0u)<<15);
        // permuted row: x = o with bits 2 and 3 swapped -> C regs == B2 k-order
        const int qts = s >> 8, ts = (s >> 5) & 7, o = s & 31;
        const int x = (o & 3) | (((o >> 2) & 1) << 3) | (((o >> 3) & 1) << 2) | (o & 16);
        unsigned* Uw = SH + ((U_BOFF + qts * 8192 + ts * 1024 + x * 32) >> 2);
        uint4 w0 = { PKB2(m, 0), PKB2(m, 2),  PKB2(m, 4),  PKB2(m, 6)  };
        uint4 w1 = { PKB2(m, 8), PKB2(m, 10), PKB2(m, 12), PKB2(m, 14) };
        *(uint4*)Uw       = w0;
        *(uint4*)(Uw + 4) = w1;

        // phase B: masks via in-wave shuffle (states frag*16..+15 live in this wave)
        const int frag = tid >> 4;     // qt*16 + t*2 + sh
        const int rp = tid & 15;       // rows 2rp, 2rp+1
        const int srcBase = ((tid >> 4) & 3) << 4;
        unsigned mm[16];
#pragma unroll
        for (int j = 0; j < 16; ++j) mm[j] = (unsigned)__shfl((int)m, srcBase + j);

        unsigned* A2w = SH + ((A2_BOFF + frag * 1024 + rp * 64) >> 2);
#pragma unroll
        for (int rr = 0; rr < 2; ++rr) {
            const int r = rp * 2 + rr;
            uint4 lo, hi;
            if (r < 16) {              // label row: bit r of 16 states
                lo = (uint4){ PKR(mm[0],mm[1],r),   PKR(mm[2],mm[3],r),
                              PKR(mm[4],mm[5],r),   PKR(mm[6],mm[7],r) };
                hi = (uint4){ PKR(mm[8],mm[9],r),   PKR(mm[10],mm[11],r),
                              PKR(mm[12],mm[13],r), PKR(mm[14],mm[15],r) };
            } else if (r == 16) {      // z-row: all ones
                lo = (uint4){0x3F803F80u,0x3F803F80u,0x3F803F80u,0x3F803F80u};
                hi = lo;
            } else {                   // padding
                lo = (uint4){0u,0u,0u,0u};
                hi = lo;
            }
            *(uint4*)(A2w + rr * 8)     = lo;
            *(uint4*)(A2w + rr * 8 + 4) = hi;
        }
    }
    __syncthreads();

    // ---------------- Per-wave operands ----------------
    float xs[8] = { fx0.x, fx0.y, fx0.z, fx0.w, fx1.x, fx1.y, fx1.z, fx1.w };
#pragma unroll
    for (int j = 0; j < 8; ++j) xs[j] *= LOG2E;

    float up = 0.f;
#pragma unroll
    for (int j = 0; j < 8; ++j) up += fmaxf(xs[j], 0.f);
    const float U2 = up + __shfl_xor(up, 32);   // col partner is lane^32
    const float nUb = -U2;
    f32x16 cin;
#pragma unroll
    for (int j = 0; j < 16; ++j) cin[j] = nUb;  // bias folded into MFMA1 C-in

    union { unsigned short s[8]; bf16x8 v; } bhi, blo;
#pragma unroll
    for (int j = 0; j < 8; ++j) {
        unsigned short hb = bf16_rne(xs[j]);
        unsigned short lb = bf16_rne(xs[j] - bf16_to_f(hb));
        bhi.s[j] = hb; blo.s[j] = lb;
    }
    const bf16x8 b1hi = bhi.v, b1lo = blo.v;

    const char* pU  = (const char*)SHB + U_BOFF  + qt * 8192  + col * 32 + kh * 16;
    const char* pA2 = (const char*)SHB + A2_BOFF + qt * 16384 + col * 32 + kh * 16;

    f32x16 cacc = 0.0f;

    // ---- Main loop: 8 tiles x (32 states x 32 cols); P in registers throughout.
    //      unroll 2 caps prefetch depth -> peak VGPR stays under the 128 cap. ----
#pragma unroll 2
    for (int t = 0; t < 8; ++t) {
        bf16x8 A1  = *(const bf16x8*)(pU + t * 1024);          // shared by hi+lo MFMA1
        bf16x8 A2a = *(const bf16x8*)(pA2 + t * 2048);         // states sh=0
        bf16x8 A2b = *(const bf16x8*)(pA2 + t * 2048 + 1024);  // states sh=1

        f32x16 pot = __builtin_amdgcn_mfma_f32_32x32x16_bf16(A1, b1lo, cin, 0, 0, 0);
        pot        = __builtin_amdgcn_mfma_f32_32x32x16_bf16(A1, b1hi, pot, 0, 0, 0);

        // exp in place (no extra 16-reg e[] block)
#pragma unroll
        for (int r = 0; r < 16; ++r) pot[r] = exp2_hw(pot[r]);

        // C regs -> B2 k-slots in ascending order (by the row permutation):
        // lane<32: regs 0..7 = states 0..7 (sh0), regs 8..15 = states 16..23 (sh1)
        // lane>=32: regs 0..7 = states 8..15,     regs 8..15 = states 24..31
        union { unsigned u[4]; bf16x8 v; } b2a, b2b;
        b2a.u[0] = cvt_pk_bf16(pot[0],  pot[1]);   b2a.u[1] = cvt_pk_bf16(pot[2],  pot[3]);
        b2a.u[2] = cvt_pk_bf16(pot[4],  pot[5]);   b2a.u[3] = cvt_pk_bf16(pot[6],  pot[7]);
        b2b.u[0] = cvt_pk_bf16(pot[8],  pot[9]);   b2b.u[1] = cvt_pk_bf16(pot[10], pot[11]);
        b2b.u[2] = cvt_pk_bf16(pot[12], pot[13]);  b2b.u[3] = cvt_pk_bf16(pot[14], pot[15]);

        cacc = __builtin_amdgcn_mfma_f32_32x32x16_bf16(A2a, b2a.v, cacc, 0, 0, 0);
        cacc = __builtin_amdgcn_mfma_f32_32x32x16_bf16(A2b, b2b.v, cacc, 0, 0, 0);
    }

    // ---- Stash partials (overlay U/A2 region; barrier first) ----
    // cacc rows: lane<32: regs0..3=labels0..3, regs4..7=labels8..11, reg8=z(row16)
    //            lane>=32: regs0..3=labels4..7, regs4..7=labels12..15
    __syncthreads();
    {
        float* pc = (float*)SHB + (w * 32 + col) * 20 + kh * 4;
        f32x4 v0 = { cacc[0], cacc[1], cacc[2], cacc[3] };
        f32x4 v1 = { cacc[4], cacc[5], cacc[6], cacc[7] };
        *(f32x4*)pc       = v0;
        *(f32x4*)(pc + 8) = v1;
        if (!kh) pc[16] = cacc[8];
    }
    __syncthreads();

    // ---- Merge quarters, write pMargin, per-block loss ----
    {
        const int cg2 = col128 >> 5, c32 = col128 & 31;
        const float* pp = (const float*)SHB;
        const int l0 = 2 * lp, l1 = l0 + 1;
        float z = 0.f, n0 = 0.f, n1 = 0.f;
#pragma unroll
        for (int q2 = 0; q2 < 4; ++q2) {
            const int base = ((q2 * 4 + cg2) * 32 + c32) * 20;
            z  += pp[base + 16];
            n0 += pp[base + l0];
            n1 += pp[base + l1];
        }
        const float invz = 1.0f / z;
        float* prow = out + 1 + (size_t)bg * LBL + 2 * lp;

        float nn[2] = { n0, n1 };
        float yr[2] = { yv.x, yv.y };
        float ls = 0.f;
#pragma unroll
        for (int r2 = 0; r2 < 2; ++r2) {
            float p = nn[r2] * invz;
            prow[r2] = p;
            float gv = yr[r2];
            float fid = sqrtf(fmaf(p, gv, 1e-8f)) + sqrtf(fmaf(1.f - p, 1.f - gv, 1e-8f));
            float pt = fmaf(p, gv, (1.f - p) * (1.f - gv));
            float at = fmaf(0.75f, gv, 0.25f * (1.f - gv));
            float om = 1.f - pt;
            ls += (1.f - fid) * at * om * om;
        }
#pragma unroll
        for (int off = 32; off; off >>= 1) ls += __shfl_down(ls, off);
        if (lane == 0) wls[w] = ls;
    }
    __syncthreads();
    if (tid == 0) {
        float t = 0.f;
#pragma unroll
        for (int i = 0; i < WAVES; ++i) t += wls[i];
        block_loss[blockIdx.x] = t;
    }
}

__global__ __launch_bounds__(256) void plm_reduce(
    const float* __restrict__ block_loss, int n, float* __restrict__ out)
{
    __shared__ float wsum[4];
    float s = 0.f;
    for (int i = threadIdx.x; i < n; i += 256) s += block_loss[i];
#pragma unroll
    for (int off = 32; off; off >>= 1) s += __shfl_down(s, off);
    const int wave = threadIdx.x >> 6;
    if ((threadIdx.x & 63) == 0) wsum[wave] = s;
    __syncthreads();
    if (threadIdx.x == 0) {
        float t = (wsum[0] + wsum[1]) + (wsum[2] + wsum[3]);
        out[0] = t * (1.0f / ((float)B_TOTAL * (float)LBL));
    }
}

extern "C" void kernel_launch(void* const* d_in, const int* in_sizes, int n_in,
                              void* d_out, int out_size, void* d_ws, size_t ws_size,
                              hipStream_t stream) {
    const float* f = (const float*)d_in[0];   // [B, 16]
    const float* y = (const float*)d_in[1];   // [B, 16]
    const int*   S = (const int*)d_in[2];     // [1024, 16]
    float* out = (float*)d_out;               // [0]=loss, [1..]=pMargin
    float* bl  = (float*)d_ws;                // 256 block partials

    plm_mfma11<<<GRID_BLOCKS, BLOCK_THREADS, 0, stream>>>(f, y, S, out, bl);
    plm_reduce<<<1, 256, 0, stream>>>(bl, GRID_BLOCKS, out);
}

// Round 14
// 15.557 us; speedup vs baseline: 1.0346x; 1.0346x over previous
//
#include <hip/hip_runtime.h>
#include <math.h>

#define LBL 16
#define B_TOTAL 32768
#define WAVES 16
#define BLOCK_THREADS 1024
#define COLS_PER_BLOCK 128
#define GRID_BLOCKS (B_TOTAL / COLS_PER_BLOCK)  // 256 = 1 block/CU

// LDS byte offsets (static 100 KB -> 1 block/CU, 16 waves = 4 waves/SIMD).
// [0, 32768)        U:  A1 table [qt][t][xrow 0..31][k=label 0..15] bf16(bit),
//                       state o=tile-offset placed at row x = swap-bits2<->3(o)
// [32768, 98304)    A2: [qt][t][sh][row 0..31][k=state 0..15] bf16;
//                       rows 0..15 = labels, row 16 = ones (z-row), 17..31 = 0
// [98304, 102400)   smask: packed 16-bit state masks, 1024 u32
#define U_BOFF     0
#define A2_BOFF    32768
#define SMASK_BOFF 98304
#define LDS_BYTES  102400

typedef __attribute__((ext_vector_type(8)))  short bf16x8;
typedef __attribute__((ext_vector_type(4)))  float f32x4;
typedef __attribute__((ext_vector_type(16))) float f32x16;

#define LOG2E 1.4426950408889634f

#if __has_builtin(__builtin_amdgcn_exp2f)
#define EXP2F __builtin_amdgcn_exp2f
#else
#define EXP2F exp2f
#endif

static __device__ __forceinline__ unsigned short bf16_rne(float x) {
    union { float f; unsigned u; } v; v.f = x;
    unsigned r = v.u + 0x7FFFu + ((v.u >> 16) & 1u);
    return (unsigned short)(r >> 16);
}
static __device__ __forceinline__ float bf16_to_f(unsigned short h) {
    union { unsigned u; float f; } v; v.u = ((unsigned)h) << 16;
    return v.f;
}
static __device__ __forceinline__ unsigned cvt_pk_bf16(float lo, float hi) {
    unsigned r;
    asm("v_cvt_pk_bf16_f32 %0, %1, %2" : "=v"(r) : "v"(lo), "v"(hi));
    return r;
}

// pack bits l, l+1 of mask m as two bf16 (1.0/0.0) in one u32
#define PKB2(m, l) (((((m) >> (l)) & 1u) ? 0x3F80u : 0u) | ((((m) >> ((l) + 1)) & 1u) ? 0x3F800000u : 0u))
// pack bit r of masks a, b as two bf16 in one u32
#define PKR(a, b, r) (((((a) >> (r)) & 1u) ? 0x3F80u : 0u) | ((((b) >> (r)) & 1u) ? 0x3F800000u : 0u))

__global__ __launch_bounds__(BLOCK_THREADS, 4) void plm_mfma13(
    const float* __restrict__ f, const float* __restrict__ y,
    const int* __restrict__ S, float* __restrict__ out,
    float* __restrict__ block_loss)
{
    __shared__ __align__(16) unsigned char SHB[LDS_BYTES];
    __shared__ float wls[WAVES];
    unsigned* SH = (unsigned*)SHB;

    const int tid = threadIdx.x;
    const int w = tid >> 6, lane = tid & 63;
    const int qt = w >> 2;            // state quarter (256 states)
    const int cg = w & 3;             // column group (32 cols)
    const int col = lane & 31;        // batch col within group == MFMA row index
    const int kh = lane >> 5;         // k-chunk half (0: k 0..7, 1: k 8..15)
    const int b = blockIdx.x * COLS_PER_BLOCK + cg * 32 + col;

    // Epilogue mapping is tid-pure: prefetch y now (latency hides under kernel)
    const int lp = tid & 7;            // label pair
    const int col128 = tid >> 3;       // 0..127
    const int bg = blockIdx.x * COLS_PER_BLOCK + col128;
    const float2 yv = *(const float2*)(y + (size_t)bg * LBL + 2 * lp);

    // f prefetch (consumed after prologue)
    const float4* fr = (const float4*)(f + (size_t)b * LBL + kh * 8);
    float4 fx0 = fr[0], fx1 = fr[1];

    // ---------------- Prologue phase A: thread = state s ----------------
    {
        const int s = tid;
        const int4* sp = (const int4*)(S + (size_t)s * LBL);
        int4 ra = sp[0], rb = sp[1], rc = sp[2], rd = sp[3];
        unsigned m = (ra.x>0?1u:0u)       | ((ra.y>0?1u:0u)<<1)  | ((ra.z>0?1u:0u)<<2)  | ((ra.w>0?1u:0u)<<3)
                   | ((rb.x>0?1u:0u)<<4)  | ((rb.y>0?1u:0u)<<5)  | ((rb.z>0?1u:0u)<<6)  | ((rb.w>0?1u:0u)<<7)
                   | ((rc.x>0?1u:0u)<<8)  | ((rc.y>0?1u:0u)<<9)  | ((rc.z>0?1u:0u)<<10) | ((rc.w>0?1u:0u)<<11)
                   | ((rd.x>0?1u:0u)<<12) | ((rd.y>0?1u:0u)<<13) | ((rd.z>0?1u:0u)<<14) | ((rd.w>0?1u:0u)<<15);
        // permuted row: x = o with bits 2 and 3 swapped -> C regs == B2 k-order
        const int qts = s >> 8, ts = (s >> 5) & 7, o = s & 31;
        const int x = (o & 3) | (((o >> 2) & 1) << 3) | (((o >> 3) & 1) << 2) | (o & 16);
        unsigned* Uw = SH + ((U_BOFF + qts * 8192 + ts * 1024 + x * 32) >> 2);
        uint4 w0 = { PKB2(m, 0), PKB2(m, 2),  PKB2(m, 4),  PKB2(m, 6)  };
        uint4 w1 = { PKB2(m, 8), PKB2(m, 10), PKB2(m, 12), PKB2(m, 14) };
        *(uint4*)Uw       = w0;
        *(uint4*)(Uw + 4) = w1;
        SH[(SMASK_BOFF >> 2) + s] = m;
    }
    __syncthreads();

    // ---------------- Prologue phase B: thread = (fragment, row-pair) ----------------
    {
        const int frag = tid >> 4;     // qt*16 + t*2 + sh; states = frag*16 .. +15
        const int rp = tid & 15;       // rows 2rp, 2rp+1
        const unsigned* mk = SH + (SMASK_BOFF >> 2) + frag * 16;
        uint4 q0 = *(const uint4*)(mk),     q1 = *(const uint4*)(mk + 4);
        uint4 q2 = *(const uint4*)(mk + 8), q3 = *(const uint4*)(mk + 12);
        unsigned mm[16] = { q0.x,q0.y,q0.z,q0.w, q1.x,q1.y,q1.z,q1.w,
                            q2.x,q2.y,q2.z,q2.w, q3.x,q3.y,q3.z,q3.w };
        unsigned* A2w = SH + ((A2_BOFF + frag * 1024 + rp * 64) >> 2);
#pragma unroll
        for (int rr = 0; rr < 2; ++rr) {
            const int r = rp * 2 + rr;
            uint4 lo, hi;
            if (r < 16) {              // label row: bit r of 16 states
                lo = (uint4){ PKR(mm[0],mm[1],r),   PKR(mm[2],mm[3],r),
                              PKR(mm[4],mm[5],r),   PKR(mm[6],mm[7],r) };
                hi = (uint4){ PKR(mm[8],mm[9],r),   PKR(mm[10],mm[11],r),
                              PKR(mm[12],mm[13],r), PKR(mm[14],mm[15],r) };
            } else if (r == 16) {      // z-row: all ones
                lo = (uint4){0x3F803F80u,0x3F803F80u,0x3F803F80u,0x3F803F80u};
                hi = lo;
            } else {                   // padding
                lo = (uint4){0u,0u,0u,0u};
                hi = lo;
            }
            *(uint4*)(A2w + rr * 8)     = lo;
            *(uint4*)(A2w + rr * 8 + 4) = hi;
        }
    }
    __syncthreads();

    // ---------------- Per-wave operands ----------------
    float xs[8] = { fx0.x, fx0.y, fx0.z, fx0.w, fx1.x, fx1.y, fx1.z, fx1.w };
#pragma unroll
    for (int j = 0; j < 8; ++j) xs[j] *= LOG2E;

    float up = 0.f;
#pragma unroll
    for (int j = 0; j < 8; ++j) up += fmaxf(xs[j], 0.f);
    const float U2 = up + __shfl_xor(up, 32);   // col partner is lane^32
    const float nUb = -U2;
    f32x16 cin;
#pragma unroll
    for (int j = 0; j < 16; ++j) cin[j] = nUb;  // bias folded into MFMA1 C-in

    union { unsigned short s[8]; bf16x8 v; } bhi, blo;
#pragma unroll
    for (int j = 0; j < 8; ++j) {
        unsigned short hb = bf16_rne(xs[j]);
        unsigned short lb = bf16_rne(xs[j] - bf16_to_f(hb));
        bhi.s[j] = hb; blo.s[j] = lb;
    }
    const bf16x8 b1hi = bhi.v, b1lo = blo.v;

    const char* pU  = (const char*)SHB + U_BOFF  + qt * 8192  + col * 32 + kh * 16;
    const char* pA2 = (const char*)SHB + A2_BOFF + qt * 16384 + col * 32 + kh * 16;

    f32x16 cacc = 0.0f;

    // ---- Main loop: 8 tiles x (32 states x 32 cols); P in registers throughout ----
#pragma unroll
    for (int t = 0; t < 8; ++t) {
        bf16x8 A1  = *(const bf16x8*)(pU + t * 1024);          // shared by hi+lo MFMA1
        bf16x8 A2a = *(const bf16x8*)(pA2 + t * 2048);         // states sh=0
        bf16x8 A2b = *(const bf16x8*)(pA2 + t * 2048 + 1024);  // states sh=1

        f32x16 pot = __builtin_amdgcn_mfma_f32_32x32x16_bf16(A1, b1lo, cin, 0, 0, 0);
        pot        = __builtin_amdgcn_mfma_f32_32x32x16_bf16(A1, b1hi, pot, 0, 0, 0);

        float e[16];
#pragma unroll
        for (int r = 0; r < 16; ++r) e[r] = EXP2F(pot[r]);

        // C regs -> B2 k-slots in ascending order (by the row permutation):
        // lane<32: regs 0..7 = states 0..7 (sh0), regs 8..15 = states 16..23 (sh1)
        // lane>=32: regs 0..7 = states 8..15,     regs 8..15 = states 24..31
        union { unsigned u[4]; bf16x8 v; } b2a, b2b;
        b2a.u[0] = cvt_pk_bf16(e[0], e[1]);   b2a.u[1] = cvt_pk_bf16(e[2], e[3]);
        b2a.u[2] = cvt_pk_bf16(e[4], e[5]);   b2a.u[3] = cvt_pk_bf16(e[6], e[7]);
        b2b.u[0] = cvt_pk_bf16(e[8], e[9]);   b2b.u[1] = cvt_pk_bf16(e[10], e[11]);
        b2b.u[2] = cvt_pk_bf16(e[12], e[13]); b2b.u[3] = cvt_pk_bf16(e[14], e[15]);

        cacc = __builtin_amdgcn_mfma_f32_32x32x16_bf16(A2a, b2a.v, cacc, 0, 0, 0);
        cacc = __builtin_amdgcn_mfma_f32_32x32x16_bf16(A2b, b2b.v, cacc, 0, 0, 0);
    }

    // ---- Stash partials (overlay U/A2 region; barrier first) ----
    // cacc rows: lane<32: regs0..3=labels0..3, regs4..7=labels8..11, reg8=z(row16)
    //            lane>=32: regs0..3=labels4..7, regs4..7=labels12..15
    __syncthreads();
    {
        float* pc = (float*)SHB + (w * 32 + col) * 20 + kh * 4;
        f32x4 v0 = { cacc[0], cacc[1], cacc[2], cacc[3] };
        f32x4 v1 = { cacc[4], cacc[5], cacc[6], cacc[7] };
        *(f32x4*)pc       = v0;
        *(f32x4*)(pc + 8) = v1;
        if (!kh) pc[16] = cacc[8];
    }
    __syncthreads();

    // ---- Merge quarters, write pMargin, per-block loss ----
    {
        const int cg2 = col128 >> 5, c32 = col128 & 31;
        const float* pp = (const float*)SHB;
        const int l0 = 2 * lp, l1 = l0 + 1;
        float z = 0.f, n0 = 0.f, n1 = 0.f;
#pragma unroll
        for (int q2 = 0; q2 < 4; ++q2) {
            const int base = ((q2 * 4 + cg2) * 32 + c32) * 20;
            z  += pp[base + 16];
            n0 += pp[base + l0];
            n1 += pp[base + l1];
        }
        const float invz = 1.0f / z;
        float* prow = out + 1 + (size_t)bg * LBL + 2 * lp;

        float nn[2] = { n0, n1 };
        float yr[2] = { yv.x, yv.y };
        float ls = 0.f;
#pragma unroll
        for (int r2 = 0; r2 < 2; ++r2) {
            float p = nn[r2] * invz;
            prow[r2] = p;
            float gv = yr[r2];
            float fid = sqrtf(fmaf(p, gv, 1e-8f)) + sqrtf(fmaf(1.f - p, 1.f - gv, 1e-8f));
            float pt = fmaf(p, gv, (1.f - p) * (1.f - gv));
            float at = fmaf(0.75f, gv, 0.25f * (1.f - gv));
            float om = 1.f - pt;
            ls += (1.f - fid) * at * om * om;
        }
#pragma unroll
        for (int off = 32; off; off >>= 1) ls += __shfl_down(ls, off);
        if (lane == 0) wls[w] = ls;
    }
    __syncthreads();
    if (tid == 0) {
        float t = 0.f;
#pragma unroll
        for (int i = 0; i < WAVES; ++i) t += wls[i];
        block_loss[blockIdx.x] = t;
    }
}

// single-wave reduce: no LDS, no barrier, minimal dispatch tail.
// Inspection-verified: 64 lanes x 4 strided loads cover block_loss[0..255];
// shfl_down tree over 64 lanes; lane 0 writes the mean.
__global__ __launch_bounds__(64) void plm_reduce64(
    const float* __restrict__ block_loss, float* __restrict__ out)
{
    const int tid = threadIdx.x;
    float s = 0.f;
#pragma unroll
    for (int i = 0; i < GRID_BLOCKS / 64; ++i)
        s += block_loss[i * 64 + tid];
#pragma unroll
    for (int off = 32; off; off >>= 1) s += __shfl_down(s, off);
    if (tid == 0) out[0] = s * (1.0f / ((float)B_TOTAL * (float)LBL));
}

extern "C" void kernel_launch(void* const* d_in, const int* in_sizes, int n_in,
                              void* d_out, int out_size, void* d_ws, size_t ws_size,
                              hipStream_t stream) {
    const float* f = (const float*)d_in[0];   // [B, 16]
    const float* y = (const float*)d_in[1];   // [B, 16]
    const int*   S = (const int*)d_in[2];     // [1024, 16]
    float* out = (float*)d_out;               // [0]=loss, [1..]=pMargin
    float* bl  = (float*)d_ws;                // 256 block partials

    plm_mfma13<<<GRID_BLOCKS, BLOCK_THREADS, 0, stream>>>(f, y, S, out, bl);
    plm_reduce64<<<1, 64, 0, stream>>>(bl, out);
}